// Round 20
// baseline (1992.172 us; speedup 1.0000x reference)
//
#include <hip/hip_runtime.h>
#include <stdint.h>

#define EMBED  512
#define HIDDEN 512
#define VOCAB  32000
#define BATCH  64
#define NPIX   196
#define MAXLEN 32
#define NBLK   256
#define NTHR   512
#define NGRP   16       // 16 groups x 16 blocks (barrier tree)

typedef float f32x4 __attribute__((ext_vector_type(4)));
typedef short bf16x8 __attribute__((ext_vector_type(8)));
typedef unsigned short ushort_t;
typedef unsigned long long u64;

// ---------- helpers ----------
__device__ __forceinline__ u64 pack_key(float v, int idx) {
    unsigned u = __float_as_uint(v);
    u = (u & 0x80000000u) ? ~u : (u | 0x80000000u);   // monotone sortable map
    return ((u64)u << 32) | (unsigned)(~(unsigned)idx); // smaller idx wins ties
}
__device__ __forceinline__ ushort_t f2bf(float x) {           // round-to-nearest-even
    unsigned u = __float_as_uint(x);
    unsigned r = (u + 0x7fffu + ((u >> 16) & 1u)) >> 16;
    return (ushort_t)r;
}
__device__ __forceinline__ float bf2f(ushort_t h) {
    return __uint_as_float(((unsigned)h) << 16);
}
__device__ __forceinline__ void cst32(unsigned* p, unsigned v) {
    __hip_atomic_store(p, v, __ATOMIC_RELAXED, __HIP_MEMORY_SCOPE_AGENT);
}
__device__ __forceinline__ u64 cld64(const u64* p) {
    return __hip_atomic_load(p, __ATOMIC_RELAXED, __HIP_MEMORY_SCOPE_AGENT);
}
// 3-way split: 8 fp32 -> bf16 H1+H2+H3 (residual ~2^-27)  [R17-verified]
__device__ __forceinline__ void split3_8(f32x4 a, f32x4 b,
                                         bf16x8& h1, bf16x8& h2, bf16x8& h3) {
    union { ushort_t s[8]; bf16x8 v; } U1, U2, U3;
#pragma unroll
    for (int e = 0; e < 4; ++e) {
        float v0 = a[e];
        ushort_t x1 = f2bf(v0); float r1 = v0 - bf2f(x1);
        ushort_t x2 = f2bf(r1); float r2 = r1 - bf2f(x2);
        U1.s[e] = x1; U2.s[e] = x2; U3.s[e] = f2bf(r2);
        float v1 = b[e];
        ushort_t y1 = f2bf(v1); float s1 = v1 - bf2f(y1);
        ushort_t y2 = f2bf(s1); float s2 = s1 - bf2f(y2);
        U1.s[4 + e] = y1; U2.s[4 + e] = y2; U3.s[4 + e] = f2bf(s2);
    }
    h1 = U1.v; h2 = U2.v; h3 = U3.v;
}

// ---------- tree grid barrier (R10-proven; R14 backoff) ----------
__device__ __forceinline__ void grid_barrier(unsigned* barws, int k, bool fence) {
    __syncthreads();
    if (threadIdx.x == 0) {
        const int grp = blockIdx.x >> 4;
        const bool leader = (blockIdx.x & 15) == 0;
        unsigned* gc = barws + (k * NGRP + grp) * 16;
        unsigned* rc = barws + 16384 + k * 16;
        unsigned* gf = barws + 17408 + (k * NGRP + grp) * 16;
        if (fence) __threadfence();
        else asm volatile("s_waitcnt vmcnt(0)" ::: "memory");
        if (!leader) {
            __hip_atomic_fetch_add(gc, 1u, __ATOMIC_RELAXED, __HIP_MEMORY_SCOPE_AGENT);
            while (__hip_atomic_fetch_add(gf, 0u, __ATOMIC_RELAXED, __HIP_MEMORY_SCOPE_AGENT) == 0u)
                __builtin_amdgcn_s_sleep(32);
        } else {
            while (__hip_atomic_fetch_add(gc, 0u, __ATOMIC_RELAXED, __HIP_MEMORY_SCOPE_AGENT) < 15u)
                __builtin_amdgcn_s_sleep(8);
            __hip_atomic_fetch_add(rc, 1u, __ATOMIC_RELAXED, __HIP_MEMORY_SCOPE_AGENT);
            while (__hip_atomic_fetch_add(rc, 0u, __ATOMIC_RELAXED, __HIP_MEMORY_SCOPE_AGENT) < (unsigned)NGRP)
                __builtin_amdgcn_s_sleep(8);
            __hip_atomic_fetch_add(gf, 1u, __ATOMIC_RELAXED, __HIP_MEMORY_SCOPE_AGENT);
        }
        asm volatile("" ::: "memory");
    }
    __syncthreads();
}

__global__ void ws_init(unsigned* barws, u64* kslab) {
    const int i = blockIdx.x * 256 + threadIdx.x;
    if (i < 33792) barws[i] = 0u;
    if (i < 31 * 1024) kslab[i] = 0ull;      // 31 steps x 64 rows x 16-u64 stride
}

// ---------- the whole decode, one persistent kernel ----------
// gates phase: 128 blocks x 16-col tiles (unit-major: tile = 4 units x 4 gates,
// cell update block-local), 8-wave split-K, W_gates 3-way fragment-packed,
// h A-operand = existing HPK frag slabs. fc phase: R19-verified.
__global__ __launch_bounds__(512, 2) void decode_all(
    const float* __restrict__ enc,
    const int*   __restrict__ captions,
    const float* __restrict__ emb,
    const float* __restrict__ W_ih, const float* __restrict__ b_ih,
    const float* __restrict__ W_hh, const float* __restrict__ b_hh,
    const float* __restrict__ W_fc, const float* __restrict__ b_fc,
    const float* __restrict__ W_init_h, const float* __restrict__ b_init_h,
    const float* __restrict__ W_init_c, const float* __restrict__ b_init_c,
    float* __restrict__ out,
    float* __restrict__ cbuf,       // [64][512] c-state (block-local units)
    unsigned* __restrict__ hhis,    // [32][16384] u32 — HPK frag-packed h comp1
    unsigned* __restrict__ hlos,    // comp2
    unsigned* __restrict__ hxs,     // comp3 (gates only)
    u64* __restrict__ kslab,        // [31][64][16] argmax keys (pre-zeroed)
    ushort_t* __restrict__ Whi, ushort_t* __restrict__ Wlo,   // fc WPK (R19)
    ushort_t* __restrict__ WG1, ushort_t* __restrict__ WG2, ushort_t* __restrict__ WG3,
    unsigned* __restrict__ barws)
{
    __shared__ __align__(16) float smem[7168];        // gates split-K dump / init summary
    __shared__ u64 kredl[512];                        // fc per-wave row maxes
    __shared__ int ltoks[BATCH];

    const int blk = blockIdx.x, tid = threadIdx.x;
    const int lane = tid & 63, w = tid >> 6;
    const int r16 = lane & 15, g = lane >> 4;

    // ---- one-time: fc wsplit W_fc -> WPK (R19-verified) ----
    {
        const int nfrag = VOCAB * 64;
        for (int i = blk * NTHR + tid; i < nfrag; i += NBLK * NTHR) {
            const int col = i >> 6, kf = i & 63;
            const int kb = kf >> 2, gw = kf & 3;
            const f32x4* src = (const f32x4*)(W_fc + (size_t)col * EMBED + kf * 8);
            f32x4 w0 = src[0], w1 = src[1];
            ushort_t hi[8], lo[8];
#pragma unroll
            for (int e = 0; e < 4; ++e) {
                hi[e] = f2bf(w0[e]);     lo[e] = f2bf(w0[e] - bf2f(hi[e]));
                hi[4+e] = f2bf(w1[e]);   lo[4+e] = f2bf(w1[e] - bf2f(hi[4+e]));
            }
            const size_t d = ((size_t)(((col >> 7) * 8 + ((col >> 4) & 7)) * 16 + kb) * 64
                              + gw * 16 + (col & 15)) * 8;
            *(uint64_t*)&Whi[d]     = *(const uint64_t*)hi;
            *(uint64_t*)&Whi[d + 4] = *(const uint64_t*)(hi + 4);
            *(uint64_t*)&Wlo[d]     = *(const uint64_t*)lo;
            *(uint64_t*)&Wlo[d + 4] = *(const uint64_t*)(lo + 4);
        }
    }
    // ---- one-time: gates W pack -> WG1/2/3 (unit-major col permutation) ----
    // frag i = ((blkg*32+kq)*64 + lfrag); lfrag = g2*16+r16; u = blkg*4+(r16>>2);
    // j = (r16&3)*512 + u; k0 = kq*32 + g2*8 (k<512 -> W_ih, else W_hh).
    {
        const int nfragG = 128 * 32 * 64;   // 262144
        for (int i = blk * NTHR + tid; i < nfragG; i += NBLK * NTHR) {
            const int blkg = i >> 11, kq = (i >> 6) & 31, lfrag = i & 63;
            const int g2 = lfrag >> 4, r16f = lfrag & 15;
            const int u = blkg * 4 + (r16f >> 2);
            const int j = (r16f & 3) * 512 + u;
            const int k0 = kq * 32 + g2 * 8;
            const float* src = (k0 < 512) ? (W_ih + (size_t)j * EMBED + k0)
                                          : (W_hh + (size_t)j * HIDDEN + (k0 - 512));
            bf16x8 b1, b2, b3;
            split3_8(*(const f32x4*)src, *(const f32x4*)(src + 4), b1, b2, b3);
            *(bf16x8*)&WG1[(size_t)i * 8] = b1;
            *(bf16x8*)&WG2[(size_t)i * 8] = b2;
            *(bf16x8*)&WG3[(size_t)i * 8] = b3;
        }
    }

    // ---- one-time: init (blocks 0..63): summary, h0 -> HPK slab0 (3 comp), c0 ----
    if (blk < BATCH) {
        const int b = blk;
        {
            float s = 0.f;
            const float* p = enc + (size_t)b * NPIX * HIDDEN + tid;
            for (int px = 0; px < NPIX; ++px) s += p[(size_t)px * HIDDEN];
            smem[tid] = s * (1.0f / NPIX);
        }
        __syncthreads();
        {
            const int j = tid;
            const f32x4* wh = (const f32x4*)(W_init_h + (size_t)j * HIDDEN);
            const f32x4* wc = (const f32x4*)(W_init_c + (size_t)j * HIDDEN);
            float ah = 0.f, ac = 0.f;
            for (int k4 = 0; k4 < HIDDEN / 4; ++k4) {
                f32x4 s4 = *(const f32x4*)&smem[k4 * 4];
                f32x4 a = wh[k4], cc = wc[k4];
                ah += s4[0]*a[0] + s4[1]*a[1] + s4[2]*a[2] + s4[3]*a[3];
                ac += s4[0]*cc[0] + s4[1]*cc[1] + s4[2]*cc[2] + s4[3]*cc[3];
            }
            ah += b_init_h[j];
            cbuf[b * HIDDEN + j] = ac + b_init_c[j];
            ushort_t c1 = f2bf(ah); float r1 = ah - bf2f(c1);
            ushort_t c2 = f2bf(r1); float r2 = r1 - bf2f(c2);
            ushort_t c3 = f2bf(r2);
            unsigned p1 = c1, p2 = c2, p3 = c3;
            unsigned q1 = __shfl_xor(p1, 1, 64);
            unsigned q2 = __shfl_xor(p2, 1, 64);
            unsigned q3 = __shfl_xor(p3, 1, 64);
            if ((j & 1) == 0) {
                const int u2 = j >> 1;
                const int mt = b >> 4, r16m = b & 15;
                const int kb = u2 >> 4, tl = u2 & 15, gg2 = tl >> 2, jj = tl & 3;
                const size_t d = (size_t)(((kb * 4 + mt) * 64) + gg2 * 16 + r16m) * 4 + jj;
                hhis[d] = p1 | (q1 << 16);
                hlos[d] = p2 | (q2 << 16);
                hxs [d] = p3 | (q3 << 16);
            }
        }
        f32x4* o4 = (f32x4*)(out + (size_t)b * MAXLEN * VOCAB);
        f32x4 z = {0.f, 0.f, 0.f, 0.f};
        for (int i = tid; i < VOCAB / 4; i += NTHR) __builtin_nontemporal_store(z, &o4[i]);
    }
    grid_barrier(barws, 0, true);

    // ======== 31 decode steps ========
    for (int t = 0; t < MAXLEN - 1; ++t) {
        const unsigned* gi1 = hhis + (size_t)t * 16384;        // h(t) comp1
        const unsigned* gi2 = hlos + (size_t)t * 16384;
        const unsigned* gi3 = hxs  + (size_t)t * 16384;
        unsigned* go1 = hhis + (size_t)(t + 1) * 16384;        // h(t+1)
        unsigned* go2 = hlos + (size_t)(t + 1) * 16384;
        unsigned* go3 = hxs  + (size_t)(t + 1) * 16384;

        // ---------- gates phase (blocks 0..127): 6-product MFMA, split-K x8 ----------
        if (blk < 128) {
            if (tid < BATCH) {
                int tok;
                if (t == 0) tok = captions[tid * MAXLEN];
                else {
                    u64 km = cld64(kslab + (size_t)(t - 1) * 1024 + tid * 16);
                    tok = (int)(~(unsigned)(km & 0xffffffffull));
                }
                ltoks[tid] = tok;
            }
            __syncthreads();

            f32x4 acc[4];
#pragma unroll
            for (int i = 0; i < 4; ++i) acc[i] = (f32x4){0.f, 0.f, 0.f, 0.f};

            const int ks = w;                   // K-slice [ks*128, +128)
            int tok4[4];
            if (ks < 4) {
#pragma unroll
                for (int mt = 0; mt < 4; ++mt) tok4[mt] = ltoks[mt * 16 + r16];
            }
#pragma unroll
            for (int kk = 0; kk < 4; ++kk) {
                const int kq = ks * 4 + kk;
                const size_t bd = ((size_t)(blk * 32 + kq) * 64 + lane) * 8;
                bf16x8 B1 = *(const bf16x8*)(WG1 + bd);
                bf16x8 B2 = *(const bf16x8*)(WG2 + bd);
                bf16x8 B3 = *(const bf16x8*)(WG3 + bd);
                bf16x8 A1[4], A2[4], A3[4];
                if (ks < 4) {                   // x half: gather emb rows, split3
#pragma unroll
                    for (int mt = 0; mt < 4; ++mt) {
                        const float* xp = emb + (size_t)tok4[mt] * EMBED + kq * 32 + g * 8;
                        split3_8(*(const f32x4*)xp, *(const f32x4*)(xp + 4),
                                 A1[mt], A2[mt], A3[mt]);
                    }
                } else {                        // h half: HPK frag slabs (coalesced)
                    const int khh = kq - 16;
#pragma unroll
                    for (int mt = 0; mt < 4; ++mt) {
                        const size_t d = (size_t)((khh * 4 + mt) * 64 + lane) * 4;
                        A1[mt] = *(const bf16x8*)(gi1 + d);
                        A2[mt] = *(const bf16x8*)(gi2 + d);
                        A3[mt] = *(const bf16x8*)(gi3 + d);
                    }
                }
#pragma unroll
                for (int mt = 0; mt < 4; ++mt) {
                    acc[mt] = __builtin_amdgcn_mfma_f32_16x16x32_bf16(A3[mt], B1, acc[mt], 0, 0, 0);
                    acc[mt] = __builtin_amdgcn_mfma_f32_16x16x32_bf16(A1[mt], B3, acc[mt], 0, 0, 0);
                    acc[mt] = __builtin_amdgcn_mfma_f32_16x16x32_bf16(A2[mt], B2, acc[mt], 0, 0, 0);
                    acc[mt] = __builtin_amdgcn_mfma_f32_16x16x32_bf16(A2[mt], B1, acc[mt], 0, 0, 0);
                    acc[mt] = __builtin_amdgcn_mfma_f32_16x16x32_bf16(A1[mt], B2, acc[mt], 0, 0, 0);
                    acc[mt] = __builtin_amdgcn_mfma_f32_16x16x32_bf16(A1[mt], B1, acc[mt], 0, 0, 0);
                }
            }
            // split-K reduce: waves 1..7 dump; wave 0 sums + cell update
            if (w != 0) {
                float* slab = smem + (w - 1) * 1024;
#pragma unroll
                for (int mt = 0; mt < 4; ++mt)
#pragma unroll
                    for (int reg = 0; reg < 4; ++reg)
                        slab[(mt * 4 + reg) * 64 + lane] = acc[mt][reg];
            }
            __syncthreads();
            if (w == 0) {
#pragma unroll
                for (int mt = 0; mt < 4; ++mt)
#pragma unroll
                    for (int reg = 0; reg < 4; ++reg) {
                        float s = acc[mt][reg];
#pragma unroll
                        for (int jw = 0; jw < 7; ++jw)
                            s += smem[jw * 1024 + (mt * 4 + reg) * 64 + lane];
                        acc[mt][reg] = s;
                    }
                const int u_loc = r16 >> 2, q = r16 & 3;
                const int U = blk * 4 + u_loc;
                const float biasl = b_ih[q * 512 + U] + b_hh[q * 512 + U];
#pragma unroll
                for (int mt = 0; mt < 4; ++mt)
#pragma unroll
                    for (int reg = 0; reg < 4; ++reg) {
                        float v = acc[mt][reg] + biasl;
                        const int base = lane & ~3;
                        float gvi = __shfl(v, base + 0, 64);
                        float gvf = __shfl(v, base + 1, 64);
                        float gvg = __shfl(v, base + 2, 64);
                        float gvo = __shfl(v, base + 3, 64);
                        const int b = mt * 16 + g * 4 + reg;
                        float cv = (q == 0) ? cbuf[b * HIDDEN + U] : 0.f;
                        float i_ = 1.f / (1.f + expf(-gvi));
                        float f_ = 1.f / (1.f + expf(-gvf));
                        float g_ = tanhf(gvg);
                        float o_ = 1.f / (1.f + expf(-gvo));
                        float c2 = f_ * cv + i_ * g_;
                        float h2 = o_ * tanhf(c2);
                        if (q == 0) cbuf[b * HIDDEN + U] = c2;
                        ushort_t c1s = f2bf(h2); float r1 = h2 - bf2f(c1s);
                        ushort_t c2s = f2bf(r1); float r2 = r1 - bf2f(c2s);
                        ushort_t c3s = f2bf(r2);
                        unsigned w1 = c1s, w2 = c2s, w3 = c3s;
                        unsigned p1 = __shfl_xor(w1, 4, 64);
                        unsigned p2 = __shfl_xor(w2, 4, 64);
                        unsigned p3 = __shfl_xor(w3, 4, 64);
                        if (q == 0 && (u_loc & 1) == 0) {
                            const int u2 = blk * 2 + (u_loc >> 1);
                            const int kb = u2 >> 4, tl = u2 & 15, gg2 = tl >> 2, jj = tl & 3;
                            const size_t d = (size_t)((kb * 4 + mt) * 64 + gg2 * 16 + (b & 15)) * 4 + jj;
                            cst32(go1 + d, w1 | (p1 << 16));
                            cst32(go2 + d, w2 | (p2 << 16));
                            cst32(go3 + d, w3 | (p3 << 16));
                        }
                    }
            }
        }
        grid_barrier(barws, 1 + 2 * t, false);

        // ---------- FC phase (R19-verified): per-wave 16-col strip, frag loads ----------
        if (blk < 250) {
            const unsigned* fhi = hhis + (size_t)(t + 1) * 16384;
            const unsigned* flo = hlos + (size_t)(t + 1) * 16384;
            const int col = blk * 128 + w * 16 + r16;

            f32x4 acc[4];
#pragma unroll
            for (int i = 0; i < 4; ++i) acc[i] = (f32x4){0.f, 0.f, 0.f, 0.f};

            const ushort_t* wb_hi = Whi + ((size_t)(blk * 8 + w) * 16) * 64 * 8 + lane * 8;
            const ushort_t* wb_lo = Wlo + ((size_t)(blk * 8 + w) * 16) * 64 * 8 + lane * 8;

#pragma unroll
            for (int kb = 0; kb < 16; ++kb) {
                bf16x8 Bh = *(const bf16x8*)(wb_hi + (size_t)kb * 512);
                bf16x8 Bl = *(const bf16x8*)(wb_lo + (size_t)kb * 512);
                bf16x8 Ah[4], Al[4];
#pragma unroll
                for (int mt = 0; mt < 4; ++mt) {
                    const size_t d = (size_t)((kb * 4 + mt) * 64 + lane) * 4;
                    Ah[mt] = *(const bf16x8*)(fhi + d);
                    Al[mt] = *(const bf16x8*)(flo + d);
                }
#pragma unroll
                for (int mt = 0; mt < 4; ++mt) {
                    acc[mt] = __builtin_amdgcn_mfma_f32_16x16x32_bf16(Al[mt], Bh, acc[mt], 0, 0, 0);
                    acc[mt] = __builtin_amdgcn_mfma_f32_16x16x32_bf16(Ah[mt], Bl, acc[mt], 0, 0, 0);
                    acc[mt] = __builtin_amdgcn_mfma_f32_16x16x32_bf16(Ah[mt], Bh, acc[mt], 0, 0, 0);
                }
            }

            const float bias = b_fc[col];
#pragma unroll
            for (int mt = 0; mt < 4; ++mt) {
                u64 rowkey[4];
#pragma unroll
                for (int reg = 0; reg < 4; ++reg) {
                    const int row = mt * 16 + g * 4 + reg;
                    float v = acc[mt][reg] + bias;
                    __builtin_nontemporal_store(v,
                        &out[(size_t)row * (MAXLEN * VOCAB) + (size_t)(t + 1) * VOCAB + col]);
                    u64 km = pack_key(v, col);
#pragma unroll
                    for (int msk = 8; msk >= 1; msk >>= 1) {
                        u64 o = __shfl_xor(km, msk, 64);
                        km = km > o ? km : o;
                    }
                    rowkey[reg] = km;
                }
                if (r16 == 0) {
#pragma unroll
                    for (int reg = 0; reg < 4; ++reg)
                        kredl[w * 64 + mt * 16 + g * 4 + reg] = rowkey[reg];
                }
            }
            __syncthreads();
            if (w == 0) {
                const int row = lane;
                u64 km = kredl[row];
#pragma unroll
                for (int jj = 1; jj < 8; ++jj) {
                    u64 k = kredl[jj * 64 + row];
                    km = k > km ? k : km;
                }
                __hip_atomic_fetch_max(kslab + (size_t)t * 1024 + row * 16, km,
                                       __ATOMIC_RELAXED, __HIP_MEMORY_SCOPE_AGENT);
            }
        }
        grid_barrier(barws, 2 + 2 * t, false);
    }
}

extern "C" void kernel_launch(void* const* d_in, const int* in_sizes, int n_in,
                              void* d_out, int out_size, void* d_ws, size_t ws_size,
                              hipStream_t stream) {
    const float* enc       = (const float*)d_in[0];
    const int*   captions  = (const int*)  d_in[1];
    const float* emb       = (const float*)d_in[2];
    const float* W_ih      = (const float*)d_in[3];
    const float* b_ih      = (const float*)d_in[4];
    const float* W_hh      = (const float*)d_in[5];
    const float* b_hh      = (const float*)d_in[6];
    const float* W_fc      = (const float*)d_in[7];
    const float* b_fc      = (const float*)d_in[8];
    const float* W_init_h  = (const float*)d_in[9];
    const float* b_init_h  = (const float*)d_in[10];
    const float* W_init_c  = (const float*)d_in[11];
    const float* b_init_c  = (const float*)d_in[12];
    float* out = (float*)d_out;

    char* wsb = (char*)d_ws;
    float*    cbuf  = (float*)(wsb + 0);            // 131072B
    u64*      kslab = (u64*)(wsb + 131072);         // 253952B -> ends 385024
    unsigned* barws = (unsigned*)(wsb + 393216);    // 135168B -> ends 528384
    unsigned* hhis  = (unsigned*)(wsb + 1048576);   // 32 x 65536B -> ends 3145728
    unsigned* hlos  = (unsigned*)(wsb + 3145728);   // -> ends 5242880
    unsigned* hxs   = (unsigned*)(wsb + 5242880);   // -> ends 7340032
    ushort_t* WG1   = (ushort_t*)(wsb + 7340032);   // 4194304B -> ends 11534336
    ushort_t* WG2   = (ushort_t*)(wsb + 11534336);  // -> ends 15728640
    ushort_t* WG3   = (ushort_t*)(wsb + 15728640);  // -> ends 19922944
    ushort_t* Whi   = (ushort_t*)(wsb + 19922944);  // 32768000B -> ends 52690944
    ushort_t* Wlo   = (ushort_t*)(wsb + 52690944);  // 32768000B -> ends 85458944

    ws_init<<<132, 256, 0, stream>>>(barws, kslab);
    decode_all<<<NBLK, NTHR, 0, stream>>>(
        enc, captions, emb, W_ih, b_ih, W_hh, b_hh, W_fc, b_fc,
        W_init_h, b_init_h, W_init_c, b_init_c,
        out, cbuf, hhis, hlos, hxs, kslab, Whi, Wlo, WG1, WG2, WG3, barws);
}